// Round 1
// baseline (36179.886 us; speedup 1.0000x reference)
//
#include <hip/hip_runtime.h>

#define GD 130              // grid extent per dim (G+2)
#define GRID_ELEMS (GD*GD*GD)
#define STATS_BYTES 1024    // 64 sums + 64 sumsq (floats) + pad

__global__ __launch_bounds__(256) void scatter_grid_k(
    const int* __restrict__ pos, int* __restrict__ grid, int n_in)
{
    int i = blockIdx.x * blockDim.x + threadIdx.x;
    if (i < n_in) {
        int x = pos[3*i], y = pos[3*i+1], z = pos[3*i+2];
        grid[(x*GD + y)*GD + z] = i;
    }
}

// One wave per output row; lane = output channel (COUT=64).
__global__ __launch_bounds__(256) void conv_stats_k(
    const float* __restrict__ feat, const float* __restrict__ W,
    const int* __restrict__ outpos, const int* __restrict__ grid,
    float* __restrict__ out, float* __restrict__ stats, int n_out)
{
    const int lane = threadIdx.x & 63;
    const int wid  = threadIdx.x >> 6;
    const int gw   = blockIdx.x * 4 + wid;
    const int nw   = gridDim.x * 4;

    float ssum = 0.f, ssq = 0.f;

    for (int r = gw; r < n_out; r += nw) {
        const int ox = outpos[3*r], oy = outpos[3*r+1], oz = outpos[3*r+2];
        float acc = 0.f;

        #pragma unroll
        for (int dx = 0; dx < 3; ++dx) {
            #pragma unroll
            for (int dy = 0; dy < 3; ++dy) {
                const int base = ((ox+dx)*GD + (oy+dy))*GD + oz;
                const int k0 = (dx*3 + dy)*3;
                const int i0 = grid[base];
                const int i1 = grid[base+1];
                const int i2 = grid[base+2];

                #pragma unroll
                for (int dz = 0; dz < 3; ++dz) {
                    const int idx = (dz == 0) ? i0 : (dz == 1) ? i1 : i2;
                    if (idx >= 0) {
                        const float4* f4 = reinterpret_cast<const float4*>(feat + (size_t)idx * 32);
                        const float* wk = W + (size_t)(k0 + dz) * 2048 + lane;
                        #pragma unroll
                        for (int c8 = 0; c8 < 8; ++c8) {
                            const float4 f = f4[c8];
                            acc = fmaf(f.x, wk[(c8*4 + 0)*64], acc);
                            acc = fmaf(f.y, wk[(c8*4 + 1)*64], acc);
                            acc = fmaf(f.z, wk[(c8*4 + 2)*64], acc);
                            acc = fmaf(f.w, wk[(c8*4 + 3)*64], acc);
                        }
                    }
                }
            }
        }

        out[(size_t)r * 64 + lane] = acc;
        ssum += acc;
        ssq  = fmaf(acc, acc, ssq);
    }

    // block reduction: 4 waves -> per-channel partials -> global atomics
    __shared__ float red_s[4][64];
    __shared__ float red_q[4][64];
    red_s[wid][lane] = ssum;
    red_q[wid][lane] = ssq;
    __syncthreads();
    if (threadIdx.x < 64) {
        const int c = threadIdx.x;
        float s = red_s[0][c] + red_s[1][c] + red_s[2][c] + red_s[3][c];
        unsafeAtomicAdd(&stats[c], s);
    } else if (threadIdx.x < 128) {
        const int c = threadIdx.x - 64;
        float q = red_q[0][c] + red_q[1][c] + red_q[2][c] + red_q[3][c];
        unsafeAtomicAdd(&stats[64 + c], q);
    }
}

__global__ __launch_bounds__(256) void bn_relu_k(
    float* __restrict__ out, const float* __restrict__ stats,
    const float* __restrict__ gamma, const float* __restrict__ beta, int n_out)
{
    __shared__ float sc[64], sh[64];
    if (threadIdx.x < 64) {
        const int c = threadIdx.x;
        const double inv_n = 1.0 / (double)n_out;
        const double mean = (double)stats[c] * inv_n;
        const double var  = (double)stats[64 + c] * inv_n - mean * mean;
        const float scale = gamma[c] * rsqrtf((float)var + 1e-5f);
        sc[c] = scale;
        sh[c] = beta[c] - (float)mean * scale;
    }
    __syncthreads();

    const size_t total4 = (size_t)n_out * 16;   // n_out*64 floats / 4
    float4* o4 = reinterpret_cast<float4*>(out);
    for (size_t t = (size_t)blockIdx.x * blockDim.x + threadIdx.x;
         t < total4; t += (size_t)gridDim.x * blockDim.x) {
        float4 v = o4[t];
        const int c = ((int)(t & 15)) * 4;
        v.x = fmaxf(fmaf(v.x, sc[c+0], sh[c+0]), 0.f);
        v.y = fmaxf(fmaf(v.y, sc[c+1], sh[c+1]), 0.f);
        v.z = fmaxf(fmaf(v.z, sc[c+2], sh[c+2]), 0.f);
        v.w = fmaxf(fmaf(v.w, sc[c+3], sh[c+3]), 0.f);
        o4[t] = v;
    }
}

extern "C" void kernel_launch(void* const* d_in, const int* in_sizes, int n_in_arrs,
                              void* d_out, int out_size, void* d_ws, size_t ws_size,
                              hipStream_t stream)
{
    const float* feat   = (const float*)d_in[0];
    const float* W      = (const float*)d_in[1];
    const float* gamma  = (const float*)d_in[2];
    const float* beta   = (const float*)d_in[3];
    const int*   pos    = (const int*)d_in[4];
    const int*   outpos = (const int*)d_in[5];

    const int n_in  = in_sizes[0] / 32;
    const int n_out = in_sizes[5] / 3;

    float* out   = (float*)d_out;
    float* stats = (float*)d_ws;
    int*   grid  = (int*)((char*)d_ws + STATS_BYTES);

    hipMemsetAsync(stats, 0, STATS_BYTES, stream);
    hipMemsetAsync(grid, 0xFF, (size_t)GRID_ELEMS * 4, stream);   // int -1

    scatter_grid_k<<<(n_in + 255) / 256, 256, 0, stream>>>(pos, grid, n_in);
    conv_stats_k<<<2048, 256, 0, stream>>>(feat, W, outpos, grid, out, stats, n_out);
    bn_relu_k<<<2048, 256, 0, stream>>>(out, stats, gamma, beta, n_out);
}

// Round 2
// 16400.145 us; speedup vs baseline: 2.2061x; 2.2061x over previous
//
#include <hip/hip_runtime.h>

#define GD 130              // grid extent per dim (G+2)
#define GRID_ELEMS (GD*GD*GD)
#define STATS_BYTES 1024    // 64 sums + 64 sumsq (floats) + pad
#define CHUNK 64            // consecutive rows per wave chunk

__global__ __launch_bounds__(256) void scatter_grid_k(
    const int* __restrict__ pos, int* __restrict__ grid, int n_in)
{
    int i = blockIdx.x * blockDim.x + threadIdx.x;
    if (i < n_in) {
        int x = pos[3*i], y = pos[3*i+1], z = pos[3*i+2];
        grid[(x*GD + y)*GD + z] = i;
    }
}

// One wave per output row; lane = output channel (COUT=64).
// Rows assigned in chunks of 64 consecutive (sorted) rows per wave for
// grid/outpos locality; chunks grid-strided for load balance.
__global__ __launch_bounds__(256, 4) void conv_stats_k(
    const float* __restrict__ feat, const float* __restrict__ W,
    const int* __restrict__ outpos, const int* __restrict__ grid,
    float* __restrict__ out, float* __restrict__ stats, int n_out)
{
    const int lane = threadIdx.x & 63;
    const int wid  = threadIdx.x >> 6;
    const int gw   = blockIdx.x * 4 + wid;
    const int nw   = gridDim.x * 4;

    const int nchunks = (n_out + CHUNK - 1) / CHUNK;

    float ssum = 0.f, ssq = 0.f;

    for (int ch = gw; ch < nchunks; ch += nw) {
        const int rend = min((ch + 1) * CHUNK, n_out);
        for (int r = ch * CHUNK; r < rend; ++r) {
            const int ox = __builtin_amdgcn_readfirstlane(outpos[3*r]);
            const int oy = __builtin_amdgcn_readfirstlane(outpos[3*r+1]);
            const int oz = __builtin_amdgcn_readfirstlane(outpos[3*r+2]);

            // issue all 27 grid probes up front (independent loads, one latency)
            int idxs[27];
            #pragma unroll
            for (int d = 0; d < 9; ++d) {
                const int dx = d / 3, dy = d % 3;
                const int base = ((ox + dx)*GD + (oy + dy))*GD + oz;
                idxs[3*d + 0] = grid[base + 0];
                idxs[3*d + 1] = grid[base + 1];
                idxs[3*d + 2] = grid[base + 2];
            }

            float acc = 0.f;
            #pragma unroll
            for (int k = 0; k < 27; ++k) {
                const int idx = idxs[k];    // compile-time index (unrolled)
                if (idx >= 0) {             // wave-uniform branch
                    const float4* f4 =
                        reinterpret_cast<const float4*>(feat + (size_t)idx * 32);
                    const float* wk = W + k * 2048 + lane;
                    #pragma unroll
                    for (int c8 = 0; c8 < 8; ++c8) {
                        const float4 f = f4[c8];
                        acc = fmaf(f.x, wk[(c8*4 + 0)*64], acc);
                        acc = fmaf(f.y, wk[(c8*4 + 1)*64], acc);
                        acc = fmaf(f.z, wk[(c8*4 + 2)*64], acc);
                        acc = fmaf(f.w, wk[(c8*4 + 3)*64], acc);
                    }
                }
            }

            out[(size_t)r * 64 + lane] = acc;
            ssum += acc;
            ssq  = fmaf(acc, acc, ssq);
        }
    }

    // block reduction: 4 waves -> per-channel partials -> global atomics
    __shared__ float red_s[4][64];
    __shared__ float red_q[4][64];
    red_s[wid][lane] = ssum;
    red_q[wid][lane] = ssq;
    __syncthreads();
    if (threadIdx.x < 64) {
        const int c = threadIdx.x;
        float s = red_s[0][c] + red_s[1][c] + red_s[2][c] + red_s[3][c];
        unsafeAtomicAdd(&stats[c], s);
    } else if (threadIdx.x < 128) {
        const int c = threadIdx.x - 64;
        float q = red_q[0][c] + red_q[1][c] + red_q[2][c] + red_q[3][c];
        unsafeAtomicAdd(&stats[64 + c], q);
    }
}

__global__ __launch_bounds__(256) void bn_relu_k(
    float* __restrict__ out, const float* __restrict__ stats,
    const float* __restrict__ gamma, const float* __restrict__ beta, int n_out)
{
    __shared__ float sc[64], sh[64];
    if (threadIdx.x < 64) {
        const int c = threadIdx.x;
        const double inv_n = 1.0 / (double)n_out;
        const double mean = (double)stats[c] * inv_n;
        const double var  = (double)stats[64 + c] * inv_n - mean * mean;
        const float scale = gamma[c] * rsqrtf((float)var + 1e-5f);
        sc[c] = scale;
        sh[c] = beta[c] - (float)mean * scale;
    }
    __syncthreads();

    const size_t total4 = (size_t)n_out * 16;   // n_out*64 floats / 4
    float4* o4 = reinterpret_cast<float4*>(out);
    for (size_t t = (size_t)blockIdx.x * blockDim.x + threadIdx.x;
         t < total4; t += (size_t)gridDim.x * blockDim.x) {
        float4 v = o4[t];
        const int c = ((int)(t & 15)) * 4;
        v.x = fmaxf(fmaf(v.x, sc[c+0], sh[c+0]), 0.f);
        v.y = fmaxf(fmaf(v.y, sc[c+1], sh[c+1]), 0.f);
        v.z = fmaxf(fmaf(v.z, sc[c+2], sh[c+2]), 0.f);
        v.w = fmaxf(fmaf(v.w, sc[c+3], sh[c+3]), 0.f);
        o4[t] = v;
    }
}

extern "C" void kernel_launch(void* const* d_in, const int* in_sizes, int n_in_arrs,
                              void* d_out, int out_size, void* d_ws, size_t ws_size,
                              hipStream_t stream)
{
    const float* feat   = (const float*)d_in[0];
    const float* W      = (const float*)d_in[1];
    const float* gamma  = (const float*)d_in[2];
    const float* beta   = (const float*)d_in[3];
    const int*   pos    = (const int*)d_in[4];
    const int*   outpos = (const int*)d_in[5];

    const int n_in  = in_sizes[0] / 32;
    const int n_out = in_sizes[5] / 3;

    float* out   = (float*)d_out;
    float* stats = (float*)d_ws;
    int*   grid  = (int*)((char*)d_ws + STATS_BYTES);

    hipMemsetAsync(stats, 0, STATS_BYTES, stream);
    hipMemsetAsync(grid, 0xFF, (size_t)GRID_ELEMS * 4, stream);   // int -1

    scatter_grid_k<<<(n_in + 255) / 256, 256, 0, stream>>>(pos, grid, n_in);
    conv_stats_k<<<2048, 256, 0, stream>>>(feat, W, outpos, grid, out, stats, n_out);
    bn_relu_k<<<2048, 256, 0, stream>>>(out, stats, gamma, beta, n_out);
}

// Round 3
// 1047.975 us; speedup vs baseline: 34.5236x; 15.6494x over previous
//
#include <hip/hip_runtime.h>

#define GD 130              // grid extent per dim (G+2)
#define GRID_ELEMS (GD*GD*GD)
#define STATS_BYTES 1024    // 64 sums + 64 sumsq (floats) + pad
#define CHUNK 64            // consecutive rows per wave chunk
#define WPB 16              // waves per conv block (1024 threads)
#define CONV_BLOCKS 256     // 1 block/CU, persistent

__device__ __forceinline__ unsigned short f32_to_bf16_rne(float x) {
    unsigned int u = __float_as_uint(x);
    u += 0x7fffu + ((u >> 16) & 1u);      // round-to-nearest-even
    return (unsigned short)(u >> 16);
}

__global__ __launch_bounds__(256) void scatter_grid_k(
    const int* __restrict__ pos, int* __restrict__ grid, int n_in)
{
    int i = blockIdx.x * blockDim.x + threadIdx.x;
    if (i < n_in) {
        int x = pos[3*i], y = pos[3*i+1], z = pos[3*i+2];
        grid[(x*GD + y)*GD + z] = i;
    }
}

// One wave per output row; lane = output channel (COUT=64).
// Weights staged once per block into LDS as bf16, layout [k][cout][cin]
// so each lane reads its 32 cin-weights contiguously (4x ds_read_b128).
__global__ __launch_bounds__(1024, 4) void conv_stats_k(
    const float* __restrict__ feat, const float* __restrict__ W,
    const int* __restrict__ outpos, const int* __restrict__ grid,
    float* __restrict__ out, float* __restrict__ stats, int n_out)
{
    __shared__ unsigned short wlds[27*64*32];   // 110,592 B
    __shared__ float sstat[128];

    const int tid  = threadIdx.x;
    const int lane = tid & 63;
    const int wid  = tid >> 6;

    // --- stage W: global [k][cin][cout] f32 -> LDS [k][cout][cin] bf16 ---
    for (int i = tid; i < 27*32*64; i += 1024) {
        const int k = i >> 11;            // /2048
        const int rem = i & 2047;
        const int c = rem >> 6;           // cin
        const int o = rem & 63;           // cout
        wlds[(k*64 + o)*32 + c] = f32_to_bf16_rne(W[i]);
    }
    if (tid < 128) sstat[tid] = 0.f;
    __syncthreads();

    const int gw = blockIdx.x * WPB + wid;
    const int nw = gridDim.x * WPB;
    const int nchunks = (n_out + CHUNK - 1) / CHUNK;

    float ssum = 0.f, ssq = 0.f;

    const uint4* wl = reinterpret_cast<const uint4*>(wlds);  // 1 uint4 = 8 bf16

    for (int ch = gw; ch < nchunks; ch += nw) {
        const int rend = min((ch + 1) * CHUNK, n_out);
        for (int r = ch * CHUNK; r < rend; ++r) {
            const int ox = __builtin_amdgcn_readfirstlane(outpos[3*r]);
            const int oy = __builtin_amdgcn_readfirstlane(outpos[3*r+1]);
            const int oz = __builtin_amdgcn_readfirstlane(outpos[3*r+2]);

            // issue all 27 grid probes up front (independent scalar loads)
            int idxs[27];
            #pragma unroll
            for (int d = 0; d < 9; ++d) {
                const int dx = d / 3, dy = d % 3;
                const int base = ((ox + dx)*GD + (oy + dy))*GD + oz;
                idxs[3*d + 0] = grid[base + 0];
                idxs[3*d + 1] = grid[base + 1];
                idxs[3*d + 2] = grid[base + 2];
            }

            float acc = 0.f;
            #pragma unroll
            for (int k = 0; k < 27; ++k) {
                const int idx = idxs[k];        // static index (unrolled)
                if (idx >= 0) {                 // wave-uniform branch
                    const float4* f4 =
                        reinterpret_cast<const float4*>(feat + (size_t)idx * 32);
                    // lane's weight row: 32 bf16 = 4 uint4
                    const uint4* wr = wl + ((k*64 + lane) * 32) / 8;
                    #pragma unroll
                    for (int q = 0; q < 4; ++q) {
                        const uint4 w = wr[q];
                        const float4 f0 = f4[2*q + 0];
                        const float4 f1 = f4[2*q + 1];
                        acc = fmaf(f0.x, __uint_as_float(w.x << 16),        acc);
                        acc = fmaf(f0.y, __uint_as_float(w.x & 0xffff0000u), acc);
                        acc = fmaf(f0.z, __uint_as_float(w.y << 16),        acc);
                        acc = fmaf(f0.w, __uint_as_float(w.y & 0xffff0000u), acc);
                        acc = fmaf(f1.x, __uint_as_float(w.z << 16),        acc);
                        acc = fmaf(f1.y, __uint_as_float(w.z & 0xffff0000u), acc);
                        acc = fmaf(f1.z, __uint_as_float(w.w << 16),        acc);
                        acc = fmaf(f1.w, __uint_as_float(w.w & 0xffff0000u), acc);
                    }
                }
            }

            out[(size_t)r * 64 + lane] = acc;
            ssum += acc;
            ssq  = fmaf(acc, acc, ssq);
        }
    }

    // block reduction via LDS atomics, then one global atomic per channel
    atomicAdd(&sstat[lane],      ssum);
    atomicAdd(&sstat[64 + lane], ssq);
    __syncthreads();
    if (tid < 128) unsafeAtomicAdd(&stats[tid], sstat[tid]);
}

__global__ __launch_bounds__(256) void bn_relu_k(
    float* __restrict__ out, const float* __restrict__ stats,
    const float* __restrict__ gamma, const float* __restrict__ beta, int n_out)
{
    __shared__ float sc[64], sh[64];
    if (threadIdx.x < 64) {
        const int c = threadIdx.x;
        const double inv_n = 1.0 / (double)n_out;
        const double mean = (double)stats[c] * inv_n;
        const double var  = (double)stats[64 + c] * inv_n - mean * mean;
        const float scale = gamma[c] * rsqrtf((float)var + 1e-5f);
        sc[c] = scale;
        sh[c] = beta[c] - (float)mean * scale;
    }
    __syncthreads();

    const size_t total4 = (size_t)n_out * 16;   // n_out*64 floats / 4
    float4* o4 = reinterpret_cast<float4*>(out);
    for (size_t t = (size_t)blockIdx.x * blockDim.x + threadIdx.x;
         t < total4; t += (size_t)gridDim.x * blockDim.x) {
        float4 v = o4[t];
        const int c = ((int)(t & 15)) * 4;
        v.x = fmaxf(fmaf(v.x, sc[c+0], sh[c+0]), 0.f);
        v.y = fmaxf(fmaf(v.y, sc[c+1], sh[c+1]), 0.f);
        v.z = fmaxf(fmaf(v.z, sc[c+2], sh[c+2]), 0.f);
        v.w = fmaxf(fmaf(v.w, sc[c+3], sh[c+3]), 0.f);
        o4[t] = v;
    }
}

extern "C" void kernel_launch(void* const* d_in, const int* in_sizes, int n_in_arrs,
                              void* d_out, int out_size, void* d_ws, size_t ws_size,
                              hipStream_t stream)
{
    const float* feat   = (const float*)d_in[0];
    const float* W      = (const float*)d_in[1];
    const float* gamma  = (const float*)d_in[2];
    const float* beta   = (const float*)d_in[3];
    const int*   pos    = (const int*)d_in[4];
    const int*   outpos = (const int*)d_in[5];

    const int n_in  = in_sizes[0] / 32;
    const int n_out = in_sizes[5] / 3;

    float* out   = (float*)d_out;
    float* stats = (float*)d_ws;
    int*   grid  = (int*)((char*)d_ws + STATS_BYTES);

    hipMemsetAsync(stats, 0, STATS_BYTES, stream);
    hipMemsetAsync(grid, 0xFF, (size_t)GRID_ELEMS * 4, stream);   // int -1

    scatter_grid_k<<<(n_in + 255) / 256, 256, 0, stream>>>(pos, grid, n_in);
    conv_stats_k<<<CONV_BLOCKS, 1024, 0, stream>>>(feat, W, outpos, grid, out, stats, n_out);
    bn_relu_k<<<2048, 256, 0, stream>>>(out, stats, gamma, beta, n_out);
}

// Round 4
// 992.360 us; speedup vs baseline: 36.4584x; 1.0560x over previous
//
#include <hip/hip_runtime.h>

#define GD 130              // grid extent per dim (G+2)
#define GRID_ELEMS (GD*GD*GD)
#define STATS_BYTES 1024    // 64 sums + 64 sumsq (floats) + pad
#define CHUNK 64            // consecutive rows per wave chunk
#define WPB 16              // waves per conv block (1024 threads)
#define CONV_BLOCKS 256     // 1 block/CU, persistent
#define MAX_NIN 100000

typedef _Float16 h2 __attribute__((ext_vector_type(2)));

__device__ _Float16 g_feat16[MAX_NIN * 32];   // 6.4 MB static; rewritten every call

__device__ __forceinline__ float dot2(unsigned int f, unsigned int w, float acc) {
    union { unsigned int u; h2 h; } a, b;
    a.u = f; b.u = w;
    return __builtin_amdgcn_fdot2(a.h, b.h, acc, false);
}

__global__ __launch_bounds__(256) void scatter_grid_k(
    const int* __restrict__ pos, int* __restrict__ grid, int n_in)
{
    int i = blockIdx.x * blockDim.x + threadIdx.x;
    if (i < n_in) {
        int x = pos[3*i], y = pos[3*i+1], z = pos[3*i+2];
        grid[(x*GD + y)*GD + z] = i;
    }
}

__global__ __launch_bounds__(256) void feat_to_f16_k(
    const float* __restrict__ feat, int n32)
{
    int i = (blockIdx.x * blockDim.x + threadIdx.x) * 8;
    if (i < n32) {
        const float4 a = *reinterpret_cast<const float4*>(feat + i);
        const float4 b = *reinterpret_cast<const float4*>(feat + i + 4);
        union { _Float16 h[8]; uint4 u; } t;
        t.h[0] = (_Float16)a.x; t.h[1] = (_Float16)a.y;
        t.h[2] = (_Float16)a.z; t.h[3] = (_Float16)a.w;
        t.h[4] = (_Float16)b.x; t.h[5] = (_Float16)b.y;
        t.h[6] = (_Float16)b.z; t.h[7] = (_Float16)b.w;
        *reinterpret_cast<uint4*>(g_feat16 + i) = t.u;
    }
}

// One wave per output row; lane = output channel (COUT=64).
// Weights in LDS as f16, layout [k][cout][cin], XOR-swizzled at 16B-granule
// level so ds_read_b128 across 64 lanes is bank-conflict-free.
__global__ __launch_bounds__(1024, 4) void conv_stats_k(
    const float* __restrict__ W,
    const int* __restrict__ outpos, const int* __restrict__ grid,
    float* __restrict__ out, float* __restrict__ stats, int n_out)
{
    __shared__ uint4 wlds[27*64*4];     // 110,592 B: 27 taps x 64 cout x 4 granules(8 f16)
    __shared__ float sstat[128];

    const int tid  = threadIdx.x;
    const int lane = tid & 63;
    const int wid  = tid >> 6;
    const int swz  = (lane >> 1) & 3;

    // --- stage W: global [k][cin][cout] f32 -> LDS [k][cout][granule^swz] f16 ---
    for (int g = tid; g < 27*64*4; g += 1024) {
        const int k   = g >> 8;           // /256
        const int rem = g & 255;
        const int o   = rem >> 2;         // cout
        const int q   = rem & 3;          // logical granule (8 cin)
        union { _Float16 h[8]; uint4 u; } t;
        #pragma unroll
        for (int j = 0; j < 8; ++j)
            t.h[j] = (_Float16)W[k*2048 + (q*8 + j)*64 + o];
        wlds[(k*64 + o)*4 + (q ^ ((o >> 1) & 3))] = t.u;
    }
    if (tid < 128) sstat[tid] = 0.f;
    __syncthreads();

    const int gw = blockIdx.x * WPB + wid;
    const int nw = gridDim.x * WPB;
    const int nchunks = (n_out + CHUNK - 1) / CHUNK;

    float ssum = 0.f, ssq = 0.f;

    for (int ch = gw; ch < nchunks; ch += nw) {
        const int rend = min((ch + 1) * CHUNK, n_out);
        for (int r = ch * CHUNK; r < rend; ++r) {
            const int ox = __builtin_amdgcn_readfirstlane(outpos[3*r]);
            const int oy = __builtin_amdgcn_readfirstlane(outpos[3*r+1]);
            const int oz = __builtin_amdgcn_readfirstlane(outpos[3*r+2]);

            // issue all 27 grid probes up front (independent scalar loads)
            int idxs[27];
            #pragma unroll
            for (int d = 0; d < 9; ++d) {
                const int dx = d / 3, dy = d % 3;
                const int base = ((ox + dx)*GD + (oy + dy))*GD + oz;
                idxs[3*d + 0] = grid[base + 0];
                idxs[3*d + 1] = grid[base + 1];
                idxs[3*d + 2] = grid[base + 2];
            }

            float acc = 0.f;
            #pragma unroll
            for (int k = 0; k < 27; ++k) {
                const int idx = idxs[k];        // static index (unrolled)
                if (idx >= 0) {                 // wave-uniform branch
                    const uint4* fp =
                        reinterpret_cast<const uint4*>(g_feat16 + (size_t)idx * 32);
                    const uint4* wrow = wlds + (k*64 + lane)*4;
                    #pragma unroll
                    for (int q = 0; q < 4; ++q) {
                        const uint4 f = fp[q];
                        const uint4 w = wrow[q ^ swz];
                        acc = dot2(f.x, w.x, acc);
                        acc = dot2(f.y, w.y, acc);
                        acc = dot2(f.z, w.z, acc);
                        acc = dot2(f.w, w.w, acc);
                    }
                }
            }

            out[(size_t)r * 64 + lane] = acc;
            ssum += acc;
            ssq  = fmaf(acc, acc, ssq);
        }
    }

    // block reduction via LDS atomics, then one global atomic per channel
    atomicAdd(&sstat[lane],      ssum);
    atomicAdd(&sstat[64 + lane], ssq);
    __syncthreads();
    if (tid < 128) unsafeAtomicAdd(&stats[tid], sstat[tid]);
}

__global__ __launch_bounds__(256) void bn_relu_k(
    float* __restrict__ out, const float* __restrict__ stats,
    const float* __restrict__ gamma, const float* __restrict__ beta, int n_out)
{
    __shared__ float sc[64], sh[64];
    if (threadIdx.x < 64) {
        const int c = threadIdx.x;
        const double inv_n = 1.0 / (double)n_out;
        const double mean = (double)stats[c] * inv_n;
        const double var  = (double)stats[64 + c] * inv_n - mean * mean;
        const float scale = gamma[c] * rsqrtf((float)var + 1e-5f);
        sc[c] = scale;
        sh[c] = beta[c] - (float)mean * scale;
    }
    __syncthreads();

    const size_t total4 = (size_t)n_out * 16;   // n_out*64 floats / 4
    float4* o4 = reinterpret_cast<float4*>(out);
    for (size_t t = (size_t)blockIdx.x * blockDim.x + threadIdx.x;
         t < total4; t += (size_t)gridDim.x * blockDim.x) {
        float4 v = o4[t];
        const int c = ((int)(t & 15)) * 4;
        v.x = fmaxf(fmaf(v.x, sc[c+0], sh[c+0]), 0.f);
        v.y = fmaxf(fmaf(v.y, sc[c+1], sh[c+1]), 0.f);
        v.z = fmaxf(fmaf(v.z, sc[c+2], sh[c+2]), 0.f);
        v.w = fmaxf(fmaf(v.w, sc[c+3], sh[c+3]), 0.f);
        o4[t] = v;
    }
}

extern "C" void kernel_launch(void* const* d_in, const int* in_sizes, int n_in_arrs,
                              void* d_out, int out_size, void* d_ws, size_t ws_size,
                              hipStream_t stream)
{
    const float* feat   = (const float*)d_in[0];
    const float* W      = (const float*)d_in[1];
    const float* gamma  = (const float*)d_in[2];
    const float* beta   = (const float*)d_in[3];
    const int*   pos    = (const int*)d_in[4];
    const int*   outpos = (const int*)d_in[5];

    const int n_in  = in_sizes[0] / 32;
    const int n_out = in_sizes[5] / 3;

    float* out   = (float*)d_out;
    float* stats = (float*)d_ws;
    int*   grid  = (int*)((char*)d_ws + STATS_BYTES);

    hipMemsetAsync(stats, 0, STATS_BYTES, stream);
    hipMemsetAsync(grid, 0xFF, (size_t)GRID_ELEMS * 4, stream);   // int -1

    scatter_grid_k<<<(n_in + 255) / 256, 256, 0, stream>>>(pos, grid, n_in);
    feat_to_f16_k<<<(n_in * 32 / 8 + 255) / 256, 256, 0, stream>>>(feat, n_in * 32);
    conv_stats_k<<<CONV_BLOCKS, 1024, 0, stream>>>(W, outpos, grid, out, stats, n_out);
    bn_relu_k<<<2048, 256, 0, stream>>>(out, stats, gamma, beta, n_out);
}

// Round 5
// 540.300 us; speedup vs baseline: 66.9626x; 1.8367x over previous
//
#include <hip/hip_runtime.h>

#define GD 130              // grid extent per dim (G+2)
#define GD2 (GD*GD)
#define GRID_ELEMS (GD*GD*GD)
#define STATS_BYTES 1024    // 64 sums + 64 sumsq (floats) + pad
#define CHUNK 64            // consecutive rows per wave chunk
#define RB 4                // rows per probe batch (108 pairs -> 2 vector loads)
#define WPB 16              // waves per conv block (1024 threads)
#define CONV_BLOCKS 256
#define MAX_NIN 100000

typedef _Float16 h2 __attribute__((ext_vector_type(2)));

__device__ _Float16 g_feat16[MAX_NIN * 32];   // 6.4 MB static; rewritten every call

__device__ __forceinline__ float dot2(unsigned int f, unsigned int w, float acc) {
    union { unsigned int u; h2 h; } a, b;
    a.u = f; b.u = w;
    return __builtin_amdgcn_fdot2(a.h, b.h, acc, false);
}

__global__ __launch_bounds__(256) void scatter_grid_k(
    const int* __restrict__ pos, int* __restrict__ grid, int n_in)
{
    int i = blockIdx.x * blockDim.x + threadIdx.x;
    if (i < n_in) {
        int x = pos[3*i], y = pos[3*i+1], z = pos[3*i+2];
        grid[(x*GD + y)*GD + z] = i;
    }
}

__global__ __launch_bounds__(256) void feat_to_f16_k(
    const float* __restrict__ feat, int n32)
{
    int i = (blockIdx.x * blockDim.x + threadIdx.x) * 8;
    if (i < n32) {
        const float4 a = *reinterpret_cast<const float4*>(feat + i);
        const float4 b = *reinterpret_cast<const float4*>(feat + i + 4);
        union { _Float16 h[8]; uint4 u; } t;
        t.h[0] = (_Float16)a.x; t.h[1] = (_Float16)a.y;
        t.h[2] = (_Float16)a.z; t.h[3] = (_Float16)a.w;
        t.h[4] = (_Float16)b.x; t.h[5] = (_Float16)b.y;
        t.h[6] = (_Float16)b.z; t.h[7] = (_Float16)b.w;
        *reinterpret_cast<uint4*>(g_feat16 + i) = t.u;
    }
}

// Process one 64-bit occupancy mask: iterate set bits (occupied taps),
// rolling accumulator flushed on row change. All control flow wave-uniform.
#define PROCESS_MASK(MASK, VIDX, POFF)                                        \
    while (MASK) {                                                            \
        const int s = (int)__builtin_ctzll(MASK);                             \
        MASK &= MASK - 1;                                                     \
        const int p = s + (POFF);                                             \
        const int r = (p * 19) >> 9;          /* p/27 for p<108 */            \
        const int t = p - 27 * r;                                             \
        const int idx = __builtin_amdgcn_readlane(VIDX, s);                   \
        const int rowg = row0 + r;                                            \
        if (rowg != cur_r) {                                                  \
            if (cur_r >= 0) {                                                 \
                const float a = a0 + a1;                                      \
                out[(size_t)cur_r * 64 + lane] = a;                           \
                ssum += a; ssq = fmaf(a, a, ssq);                             \
            }                                                                 \
            cur_r = rowg; a0 = 0.f; a1 = 0.f;                                 \
        }                                                                     \
        const uint4* fp = reinterpret_cast<const uint4*>(                     \
            g_feat16 + (size_t)idx * 32);                                     \
        const uint4* wrow = wlds + (t * 64 + lane) * 4;                       \
        const uint4 f0 = fp[0], f1 = fp[1], f2 = fp[2], f3 = fp[3];           \
        const uint4 w0 = wrow[0 ^ swz], w1 = wrow[1 ^ swz];                   \
        const uint4 w2 = wrow[2 ^ swz], w3 = wrow[3 ^ swz];                   \
        a0 = dot2(f0.x, w0.x, a0); a1 = dot2(f0.y, w0.y, a1);                 \
        a0 = dot2(f0.z, w0.z, a0); a1 = dot2(f0.w, w0.w, a1);                 \
        a0 = dot2(f1.x, w1.x, a0); a1 = dot2(f1.y, w1.y, a1);                 \
        a0 = dot2(f1.z, w1.z, a0); a1 = dot2(f1.w, w1.w, a1);                 \
        a0 = dot2(f2.x, w2.x, a0); a1 = dot2(f2.y, w2.y, a1);                 \
        a0 = dot2(f2.z, w2.z, a0); a1 = dot2(f2.w, w2.w, a1);                 \
        a0 = dot2(f3.x, w3.x, a0); a1 = dot2(f3.y, w3.y, a1);                 \
        a0 = dot2(f3.z, w3.z, a0); a1 = dot2(f3.w, w3.w, a1);                 \
    }

__global__ __launch_bounds__(1024, 4) void conv_stats_k(
    const float* __restrict__ W,
    const int* __restrict__ outpos, const int* __restrict__ grid,
    float* __restrict__ out, float* __restrict__ stats, int n_out)
{
    __shared__ uint4 wlds[27*64*4];     // 110,592 B
    __shared__ float sstat[128];

    const int tid  = threadIdx.x;
    const int lane = tid & 63;
    const int wid  = tid >> 6;
    const int swz  = (lane >> 1) & 3;

    // --- stage W: global [k][cin][cout] f32 -> LDS [k][cout][granule^swz] f16
    for (int g = tid; g < 27*64*4; g += 1024) {
        const int k   = g >> 8;
        const int rem = g & 255;
        const int o   = rem >> 2;
        const int q   = rem & 3;
        union { _Float16 h[8]; uint4 u; } t;
        #pragma unroll
        for (int j = 0; j < 8; ++j)
            t.h[j] = (_Float16)W[k*2048 + (q*8 + j)*64 + o];
        wlds[(k*64 + o)*4 + (q ^ ((o >> 1) & 3))] = t.u;
    }
    if (tid < 128) sstat[tid] = 0.f;
    __syncthreads();

    // per-lane (row,tap) pair decomposition for the two probe loads
    const int pA = lane;                      // pairs 0..63
    const int pB = lane + 64;                 // pairs 64..107 (lanes 0..43)
    const int rA = (pA * 19) >> 9;
    const int tA = pA - 27 * rA;
    const int rBv = (pB * 19) >> 9;
    const int tB = pB - 27 * rBv;
    const bool laneB = (lane < 44);

    // tap -> grid offset
    auto coff = [](int t) {
        const int dx  = (t * 114) >> 10;      // t/9
        const int rem = t - 9 * dx;
        const int dy  = (rem * 11) >> 5;      // rem/3
        const int dz  = rem - 3 * dy;
        return dx * GD2 + dy * GD + dz;
    };
    const int cA = coff(tA);
    const int cB = coff(tB);

    const int gw = blockIdx.x * WPB + wid;
    const int nw = gridDim.x * WPB;
    const int nchunks = (n_out + CHUNK - 1) / CHUNK;

    float ssum = 0.f, ssq = 0.f;

    for (int ch = gw; ch < nchunks; ch += nw) {
        const int rbase = ch * CHUNK;
        for (int b = 0; b < CHUNK / RB; ++b) {
            const int row0 = rbase + b * RB;
            if (row0 >= n_out) break;

            // probe phase: each lane probes its (row,tap) pair
            const int rowA = row0 + rA;
            const int rowB = row0 + rBv;
            const int raC = min(rowA, n_out - 1);
            const int rbC = min(rowB, n_out - 1);
            const int xA = outpos[3*raC], yA = outpos[3*raC+1], zA = outpos[3*raC+2];
            const int xB = outpos[3*rbC], yB = outpos[3*rbC+1], zB = outpos[3*rbC+2];
            int iA = grid[(xA*GD + yA)*GD + zA + cA];
            int iB = grid[(xB*GD + yB)*GD + zB + cB];
            if (rowA >= n_out) iA = -1;
            if (!laneB || rowB >= n_out) iB = -1;

            unsigned long long m0 = __ballot(iA >= 0);
            unsigned long long m1 = __ballot(iB >= 0);

            int cur_r = -1;
            float a0 = 0.f, a1 = 0.f;

            PROCESS_MASK(m0, iA, 0)
            PROCESS_MASK(m1, iB, 64)

            if (cur_r >= 0) {
                const float a = a0 + a1;
                out[(size_t)cur_r * 64 + lane] = a;
                ssum += a; ssq = fmaf(a, a, ssq);
            }
        }
    }

    // block reduction via LDS atomics, then one global atomic per channel
    atomicAdd(&sstat[lane],      ssum);
    atomicAdd(&sstat[64 + lane], ssq);
    __syncthreads();
    if (tid < 128) unsafeAtomicAdd(&stats[tid], sstat[tid]);
}

__global__ __launch_bounds__(256) void bn_relu_k(
    float* __restrict__ out, const float* __restrict__ stats,
    const float* __restrict__ gamma, const float* __restrict__ beta, int n_out)
{
    __shared__ float sc[64], sh[64];
    if (threadIdx.x < 64) {
        const int c = threadIdx.x;
        const double inv_n = 1.0 / (double)n_out;
        const double mean = (double)stats[c] * inv_n;
        const double var  = (double)stats[64 + c] * inv_n - mean * mean;
        const float scale = gamma[c] * rsqrtf((float)var + 1e-5f);
        sc[c] = scale;
        sh[c] = beta[c] - (float)mean * scale;
    }
    __syncthreads();

    const size_t total4 = (size_t)n_out * 16;   // n_out*64 floats / 4
    float4* o4 = reinterpret_cast<float4*>(out);
    for (size_t t = (size_t)blockIdx.x * blockDim.x + threadIdx.x;
         t < total4; t += (size_t)gridDim.x * blockDim.x) {
        float4 v = o4[t];
        const int c = ((int)(t & 15)) * 4;
        v.x = fmaxf(fmaf(v.x, sc[c+0], sh[c+0]), 0.f);
        v.y = fmaxf(fmaf(v.y, sc[c+1], sh[c+1]), 0.f);
        v.z = fmaxf(fmaf(v.z, sc[c+2], sh[c+2]), 0.f);
        v.w = fmaxf(fmaf(v.w, sc[c+3], sh[c+3]), 0.f);
        o4[t] = v;
    }
}

extern "C" void kernel_launch(void* const* d_in, const int* in_sizes, int n_in_arrs,
                              void* d_out, int out_size, void* d_ws, size_t ws_size,
                              hipStream_t stream)
{
    const float* feat   = (const float*)d_in[0];
    const float* W      = (const float*)d_in[1];
    const float* gamma  = (const float*)d_in[2];
    const float* beta   = (const float*)d_in[3];
    const int*   pos    = (const int*)d_in[4];
    const int*   outpos = (const int*)d_in[5];

    const int n_in  = in_sizes[0] / 32;
    const int n_out = in_sizes[5] / 3;

    float* out   = (float*)d_out;
    float* stats = (float*)d_ws;
    int*   grid  = (int*)((char*)d_ws + STATS_BYTES);

    hipMemsetAsync(stats, 0, STATS_BYTES, stream);
    hipMemsetAsync(grid, 0xFF, (size_t)GRID_ELEMS * 4, stream);   // int -1

    scatter_grid_k<<<(n_in + 255) / 256, 256, 0, stream>>>(pos, grid, n_in);
    feat_to_f16_k<<<(n_in * 32 / 8 + 255) / 256, 256, 0, stream>>>(feat, n_in * 32);
    conv_stats_k<<<CONV_BLOCKS, 1024, 0, stream>>>(W, outpos, grid, out, stats, n_out);
    bn_relu_k<<<2048, 256, 0, stream>>>(out, stats, gamma, beta, n_out);
}

// Round 6
// 538.948 us; speedup vs baseline: 67.1306x; 1.0025x over previous
//
#include <hip/hip_runtime.h>

#define GD 130              // grid extent per dim (G+2)
#define GD2 (GD*GD)
#define GRID_ELEMS (GD*GD*GD)
#define STATS_BYTES 1024    // 64 sums + 64 sumsq (floats) + pad
#define CHUNK 64            // consecutive rows per wave chunk
#define RB 4                // rows per probe batch (108 pairs -> 2 vector loads)
#define WPB 16              // waves per conv block (1024 threads)
#define CONV_BLOCKS 256
#define MAX_NIN 100000
#define WSTRIDE 5           // granules per (tap,cout) row: pad 4->5, conflict-free

typedef _Float16 h2 __attribute__((ext_vector_type(2)));

__device__ _Float16 g_feat16[MAX_NIN * 32];   // 6.4 MB static; rewritten every call

__device__ __forceinline__ float dot2(unsigned int f, unsigned int w, float acc) {
    union { unsigned int u; h2 h; } a, b;
    a.u = f; b.u = w;
    return __builtin_amdgcn_fdot2(a.h, b.h, acc, false);
}

__global__ __launch_bounds__(256) void scatter_grid_k(
    const int* __restrict__ pos, int* __restrict__ grid, int n_in)
{
    int i = blockIdx.x * blockDim.x + threadIdx.x;
    if (i < n_in) {
        int x = pos[3*i], y = pos[3*i+1], z = pos[3*i+2];
        grid[(x*GD + y)*GD + z] = i;
    }
}

__global__ __launch_bounds__(256) void feat_to_f16_k(
    const float* __restrict__ feat, int n32)
{
    int i = (blockIdx.x * blockDim.x + threadIdx.x) * 8;
    if (i < n32) {
        const float4 a = *reinterpret_cast<const float4*>(feat + i);
        const float4 b = *reinterpret_cast<const float4*>(feat + i + 4);
        union { _Float16 h[8]; uint4 u; } t;
        t.h[0] = (_Float16)a.x; t.h[1] = (_Float16)a.y;
        t.h[2] = (_Float16)a.z; t.h[3] = (_Float16)a.w;
        t.h[4] = (_Float16)b.x; t.h[5] = (_Float16)b.y;
        t.h[6] = (_Float16)b.z; t.h[7] = (_Float16)b.w;
        *reinterpret_cast<uint4*>(g_feat16 + i) = t.u;
    }
}

// Process one 64-bit occupancy mask: iterate set bits (occupied taps),
// rolling accumulator flushed on row change. All control flow wave-uniform.
#define PROCESS_MASK(MASK, VIDX, POFF)                                        \
    while (MASK) {                                                            \
        const int s = (int)__builtin_ctzll(MASK);                             \
        MASK &= MASK - 1;                                                     \
        const int p = s + (POFF);                                             \
        const int r = (p * 19) >> 9;          /* p/27 for p<108 */            \
        const int t = p - 27 * r;                                             \
        const int idx = __builtin_amdgcn_readlane(VIDX, s);                   \
        const int rowg = row0 + r;                                            \
        if (rowg != cur_r) {                                                  \
            if (cur_r >= 0) {                                                 \
                const float a = a0 + a1;                                      \
                out[(size_t)cur_r * 64 + lane] = a;                           \
                ssum += a; ssq = fmaf(a, a, ssq);                             \
            }                                                                 \
            cur_r = rowg; a0 = 0.f; a1 = 0.f;                                 \
        }                                                                     \
        const uint4* fp = reinterpret_cast<const uint4*>(                     \
            g_feat16 + (size_t)idx * 32);                                     \
        const uint4* wrow = wlds + (t * 64 + lane) * WSTRIDE;                 \
        const uint4 f0 = fp[0], f1 = fp[1], f2 = fp[2], f3 = fp[3];           \
        const uint4 w0 = wrow[0], w1 = wrow[1];                               \
        const uint4 w2 = wrow[2], w3 = wrow[3];                               \
        a0 = dot2(f0.x, w0.x, a0); a1 = dot2(f0.y, w0.y, a1);                 \
        a0 = dot2(f0.z, w0.z, a0); a1 = dot2(f0.w, w0.w, a1);                 \
        a0 = dot2(f1.x, w1.x, a0); a1 = dot2(f1.y, w1.y, a1);                 \
        a0 = dot2(f1.z, w1.z, a0); a1 = dot2(f1.w, w1.w, a1);                 \
        a0 = dot2(f2.x, w2.x, a0); a1 = dot2(f2.y, w2.y, a1);                 \
        a0 = dot2(f2.z, w2.z, a0); a1 = dot2(f2.w, w2.w, a1);                 \
        a0 = dot2(f3.x, w3.x, a0); a1 = dot2(f3.y, w3.y, a1);                 \
        a0 = dot2(f3.z, w3.z, a0); a1 = dot2(f3.w, w3.w, a1);                 \
    }

__global__ __launch_bounds__(1024, 4) void conv_stats_k(
    const float* __restrict__ W,
    const int* __restrict__ outpos, const int* __restrict__ grid,
    float* __restrict__ out, float* __restrict__ stats, int n_out)
{
    __shared__ uint4 wlds[27*64*WSTRIDE];   // 138,240 B (padded, conflict-free)
    __shared__ float sstat[128];

    const int tid  = threadIdx.x;
    const int lane = tid & 63;
    const int wid  = tid >> 6;

    // --- stage W: global [k][cin][cout] f32 -> LDS [k][cout][granule] f16
    for (int g = tid; g < 27*64*4; g += 1024) {
        const int k   = g >> 8;
        const int rem = g & 255;
        const int o   = rem >> 2;
        const int q   = rem & 3;
        union { _Float16 h[8]; uint4 u; } t;
        #pragma unroll
        for (int j = 0; j < 8; ++j)
            t.h[j] = (_Float16)W[k*2048 + (q*8 + j)*64 + o];
        wlds[(k*64 + o)*WSTRIDE + q] = t.u;
    }
    if (tid < 128) sstat[tid] = 0.f;
    __syncthreads();

    // per-lane (row,tap) pair decomposition for the two probe loads
    const int pA = lane;                      // pairs 0..63
    const int pB = lane + 64;                 // pairs 64..107 (lanes 0..43)
    const int rA = (pA * 19) >> 9;
    const int tA = pA - 27 * rA;
    const int rBv = (pB * 19) >> 9;
    const int tB = pB - 27 * rBv;
    const bool laneB = (lane < 44);

    // tap -> grid offset
    auto coff = [](int t) {
        const int dx  = (t * 114) >> 10;      // t/9
        const int rem = t - 9 * dx;
        const int dy  = (rem * 11) >> 5;      // rem/3
        const int dz  = rem - 3 * dy;
        return dx * GD2 + dy * GD + dz;
    };
    const int cA = coff(tA);
    const int cB = coff(tB);

    // probe a batch of RB rows starting at row0 -> per-lane tap indices
    auto probe = [&](int row0, int& iA, int& iB) {
        const int rowA = row0 + rA;
        const int rowB = row0 + rBv;
        const int raC = min(rowA, n_out - 1);
        const int rbC = min(rowB, n_out - 1);
        const int xA = outpos[3*raC], yA = outpos[3*raC+1], zA = outpos[3*raC+2];
        const int xB = outpos[3*rbC], yB = outpos[3*rbC+1], zB = outpos[3*rbC+2];
        int a = grid[(xA*GD + yA)*GD + zA + cA];
        int b = grid[(xB*GD + yB)*GD + zB + cB];
        if (rowA >= n_out) a = -1;
        if (!laneB || rowB >= n_out) b = -1;
        iA = a; iB = b;
    };

    const int gw = blockIdx.x * WPB + wid;
    const int nw = gridDim.x * WPB;
    const int nchunks = (n_out + CHUNK - 1) / CHUNK;
    const int NB = CHUNK / RB;

    float ssum = 0.f, ssq = 0.f;

    for (int ch = gw; ch < nchunks; ch += nw) {
        const int rbase = ch * CHUNK;
        int iA_c, iB_c;
        probe(rbase, iA_c, iB_c);             // prefetch batch 0

        for (int b = 0; b < NB; ++b) {
            const int row0 = rbase + b * RB;
            if (row0 >= n_out) break;

            unsigned long long m0 = __ballot(iA_c >= 0);
            unsigned long long m1 = __ballot(iB_c >= 0);

            // issue next batch's probe loads before processing (latency hiding)
            int iA_n = -1, iB_n = -1;
            const int row0n = row0 + RB;
            if (b + 1 < NB && row0n < n_out) probe(row0n, iA_n, iB_n);

            int cur_r = -1;
            float a0 = 0.f, a1 = 0.f;

            PROCESS_MASK(m0, iA_c, 0)
            PROCESS_MASK(m1, iB_c, 64)

            if (cur_r >= 0) {
                const float a = a0 + a1;
                out[(size_t)cur_r * 64 + lane] = a;
                ssum += a; ssq = fmaf(a, a, ssq);
            }

            iA_c = iA_n; iB_c = iB_n;
        }
    }

    // block reduction via LDS atomics, then one global atomic per channel
    atomicAdd(&sstat[lane],      ssum);
    atomicAdd(&sstat[64 + lane], ssq);
    __syncthreads();
    if (tid < 128) unsafeAtomicAdd(&stats[tid], sstat[tid]);
}

__global__ __launch_bounds__(256) void bn_relu_k(
    float* __restrict__ out, const float* __restrict__ stats,
    const float* __restrict__ gamma, const float* __restrict__ beta, int n_out)
{
    __shared__ float sc[64], sh[64];
    if (threadIdx.x < 64) {
        const int c = threadIdx.x;
        const double inv_n = 1.0 / (double)n_out;
        const double mean = (double)stats[c] * inv_n;
        const double var  = (double)stats[64 + c] * inv_n - mean * mean;
        const float scale = gamma[c] * rsqrtf((float)var + 1e-5f);
        sc[c] = scale;
        sh[c] = beta[c] - (float)mean * scale;
    }
    __syncthreads();

    const size_t total4 = (size_t)n_out * 16;   // n_out*64 floats / 4
    float4* o4 = reinterpret_cast<float4*>(out);
    for (size_t t = (size_t)blockIdx.x * blockDim.x + threadIdx.x;
         t < total4; t += (size_t)gridDim.x * blockDim.x) {
        float4 v = o4[t];
        const int c = ((int)(t & 15)) * 4;
        v.x = fmaxf(fmaf(v.x, sc[c+0], sh[c+0]), 0.f);
        v.y = fmaxf(fmaf(v.y, sc[c+1], sh[c+1]), 0.f);
        v.z = fmaxf(fmaf(v.z, sc[c+2], sh[c+2]), 0.f);
        v.w = fmaxf(fmaf(v.w, sc[c+3], sh[c+3]), 0.f);
        o4[t] = v;
    }
}

extern "C" void kernel_launch(void* const* d_in, const int* in_sizes, int n_in_arrs,
                              void* d_out, int out_size, void* d_ws, size_t ws_size,
                              hipStream_t stream)
{
    const float* feat   = (const float*)d_in[0];
    const float* W      = (const float*)d_in[1];
    const float* gamma  = (const float*)d_in[2];
    const float* beta   = (const float*)d_in[3];
    const int*   pos    = (const int*)d_in[4];
    const int*   outpos = (const int*)d_in[5];

    const int n_in  = in_sizes[0] / 32;
    const int n_out = in_sizes[5] / 3;

    float* out   = (float*)d_out;
    float* stats = (float*)d_ws;
    int*   grid  = (int*)((char*)d_ws + STATS_BYTES);

    hipMemsetAsync(stats, 0, STATS_BYTES, stream);
    hipMemsetAsync(grid, 0xFF, (size_t)GRID_ELEMS * 4, stream);   // int -1

    scatter_grid_k<<<(n_in + 255) / 256, 256, 0, stream>>>(pos, grid, n_in);
    feat_to_f16_k<<<(n_in * 32 / 8 + 255) / 256, 256, 0, stream>>>(feat, n_in * 32);
    conv_stats_k<<<CONV_BLOCKS, 1024, 0, stream>>>(W, outpos, grid, out, stats, n_out);
    bn_relu_k<<<2048, 256, 0, stream>>>(out, stats, gamma, beta, n_out);
}